// Round 2
// baseline (343.171 us; speedup 1.0000x reference)
//
#include <hip/hip_runtime.h>
#include <math.h>

#define EPS 1e-9f

constexpr int Bn = 1024, Dn = 512, Un = 512;
constexpr int BM = 64;      // rows of B per block (4x4 per thread)
constexpr int BU = 64;      // cols of U per block
constexpr int DK = 16;      // k-chunk staged in LDS (16KB/block)
constexpr int NTILES = (Bn / BM) * (Un / BU);   // 128 output tiles

typedef float v4f __attribute__((ext_vector_type(4)));

// Split-K semaphores: zero-initialized (.bss); last-arriving block resets its
// slot to 0, so the invariant "all zeros between launches" survives graph replay.
__device__ int tile_cnt[NTILES];

// XOR swizzle for sL columns (proven: conflicts -> 0). Multiples of 8,
// preserves b128 alignment of 4-float groups.
__device__ __forceinline__ int swz(int d) { return ((d >> 2) & 3) << 3; }

// MODE 0: atomicAdd directly into out (small-ws fallback; out pre-zeroed)
// MODE 1: ws partials + in-kernel fused tail reduction (semaphore)
// launch_bounds(256,8): 8 blocks/CU resident (LDS 16.9KB x 8 = 135KB < 160KB,
// VGPR capped at 64) -> whole 2048-block grid co-resident, 2x latency hiding
// vs the (256,4) config that measured Occupancy=35%, VALUBusy=74%.
template <int SPLITD, int MODE>
__global__ __launch_bounds__(256, 8) void power_layer(
    const float* __restrict__ x, const float* __restrict__ w,
    const float* __restrict__ p, const float* __restrict__ bias,
    float* __restrict__ outp, float* __restrict__ wsp)
{
    constexpr int DPB    = Dn / SPLITD;
    constexpr int NCHUNK = DPB / DK;

    __shared__ float sL[DK][BM];   // sign(neg)*(log2|x+eps|+64), swizzled cols
    __shared__ float sP[DK][BU];   // p
    __shared__ float sW[DK][BU];   // w
    __shared__ float sWX[DK][BU];  // odd(p) ? -w : w

    const int tid = threadIdx.x;
    const int tx  = tid & 15;
    const int ty  = tid >> 4;
    const int tx4 = tx * 4;
    const int ty4 = ty * 4;
    const int ub = blockIdx.x * BU;
    const int bb = blockIdx.y * BM;
    const int d0 = blockIdx.z * DPB;

    // staging thread->element maps (chunk-invariant)
    const int xr  = tid >> 2;          // 0..63  (row for x tile)
    const int xdq = (tid & 3) << 2;    // 0,4,8,12 (d quad for x tile)
    const int pd  = tid >> 4;          // 0..15  (d for p/w tile)
    const int puq = (tid & 15) << 2;   // 0..60  (u quad for p/w tile)

    float4 xv, pv, wv;                 // global->reg prefetch (software pipeline)

    auto load_chunk = [&](int ch) {
        const int db = d0 + ch * DK;
        xv = *reinterpret_cast<const float4*>(&x[(size_t)(bb + xr) * Dn + db + xdq]);
        const size_t gi = (size_t)(db + pd) * Un + ub + puq;
        pv = *reinterpret_cast<const float4*>(&p[gi]);
        wv = *reinterpret_cast<const float4*>(&w[gi]);
    };

    auto stage_chunk = [&]() {
        const float* xs = reinterpret_cast<const float*>(&xv);
        #pragma unroll
        for (int j = 0; j < 4; ++j) {
            const float xe = xs[j] + EPS;
            const float La = __builtin_amdgcn_logf(fabsf(xe)) + 64.0f;
            const int dd = xdq + j;
            sL[dd][xr ^ swz(dd)] = (xe < 0.0f) ? -La : La;
        }
        const float* ps  = reinterpret_cast<const float*>(&pv);
        const float* wsv = reinterpret_cast<const float*>(&wv);
        float4 wxv;
        float* wxs = reinterpret_cast<float*>(&wxv);
        #pragma unroll
        for (int j = 0; j < 4; ++j) {
            const bool odd = (fmodf(ps[j], 2.0f) != 0.0f);
            wxs[j] = odd ? -wsv[j] : wsv[j];
        }
        *reinterpret_cast<float4*>(&sP[pd][puq])  = pv;
        *reinterpret_cast<float4*>(&sW[pd][puq])  = wv;
        *reinterpret_cast<float4*>(&sWX[pd][puq]) = wxv;
    };

    v4f acc[4] = {};   // 4 rows x 4 cols per thread

    load_chunk(0);
    stage_chunk();
    __syncthreads();

    for (int ch = 0; ch < NCHUNK; ++ch) {
        // issue next chunk's global loads now; latency hides under 16 d-iters
        if (ch + 1 < NCHUNK) load_chunk(ch + 1);

        // R0-proven inner loop: read BOTH w arrays as true LDS (ds_read_b128)
        // and select per element with v_cndmask. Do NOT select a pointer --
        // that demotes the access to flat_load (R1: 47.6us -> 290us).
        #pragma unroll 2
        for (int d = 0; d < DK; ++d) {
            const v4f Lv = *reinterpret_cast<const v4f*>(&sL[d][ty4 ^ swz(d)]);
            const v4f Pv = *reinterpret_cast<const v4f*>(&sP[d][tx4]);
            const v4f Wv = *reinterpret_cast<const v4f*>(&sW[d][tx4]);
            const v4f Xv = *reinterpret_cast<const v4f*>(&sWX[d][tx4]);

            float Ld[4];
            bool  ng[4];
            #pragma unroll
            for (int r = 0; r < 4; ++r) {
                Ld[r] = fabsf(Lv[r]) - 64.0f;
                ng[r] = Lv[r] < 0.0f;
            }

            // batch all 16 independent exps before any consumer
            v4f e[4];
            #pragma unroll
            for (int r = 0; r < 4; ++r) {
                const v4f t = Pv * Ld[r];         // v_pk_mul_f32 x2
                #pragma unroll
                for (int c = 0; c < 4; ++c)
                    e[r][c] = __builtin_amdgcn_exp2f(t[c]);
            }

            #pragma unroll
            for (int r = 0; r < 4; ++r) {
                v4f wsel;
                #pragma unroll
                for (int c = 0; c < 4; ++c)
                    wsel[c] = ng[r] ? Xv[c] : Wv[c];   // v_cndmask
                acc[r] = __builtin_elementwise_fma(wsel, e[r], acc[r]);  // v_pk_fma x2
            }
        }
        __syncthreads();
        if (ch + 1 < NCHUNK) {
            stage_chunk();          // regs (loaded above) -> LDS
            __syncthreads();
        }
    }

    if (MODE == 0) {
        if (blockIdx.z == 0) {
            const v4f bv = *reinterpret_cast<const v4f*>(&bias[ub + tx4]);
            #pragma unroll
            for (int r = 0; r < 4; ++r)
                acc[r] += bv;
        }
        #pragma unroll
        for (int r = 0; r < 4; ++r) {
            const int row = bb + ty4 + r;
            #pragma unroll
            for (int c = 0; c < 4; ++c)
                atomicAdd(&outp[(size_t)row * Un + ub + tx4 + c], acc[r][c]);
        }
        return;
    }

    // ---- MODE 1: write partial, then last-arriving z-block reduces the tile ----
    {
        float* dst = wsp + (((size_t)blockIdx.z * Bn + bb + ty4) * Un + ub + tx4);
        #pragma unroll
        for (int r = 0; r < 4; ++r)
            *reinterpret_cast<v4f*>(dst + (size_t)r * Un) = acc[r];
    }

    __threadfence();               // release our partial (agent scope)
    __syncthreads();               // all threads' stores fenced before arrive

    __shared__ int s_last;
    if (tid == 0) {
        const int tile = blockIdx.y * (Un / BU) + blockIdx.x;
        const int old = __hip_atomic_fetch_add(&tile_cnt[tile], 1,
                            __ATOMIC_ACQ_REL, __HIP_MEMORY_SCOPE_AGENT);
        s_last = (old == SPLITD - 1) ? 1 : 0;
        if (old == SPLITD - 1)     // self-clean for the next launch/replay
            __hip_atomic_store(&tile_cnt[tile], 0, __ATOMIC_RELAXED,
                               __HIP_MEMORY_SCOPE_AGENT);
    }
    __syncthreads();
    if (!s_last) return;
    __threadfence();               // acquire: drop stale lines before reading
                                   // other XCDs' partials

    const v4f bv = *reinterpret_cast<const v4f*>(&bias[ub + tx4]);
    v4f sum[4] = {bv, bv, bv, bv};
    const float* srcBase = wsp + ((size_t)(bb + ty4) * Un + ub + tx4);
    for (int z = 0; z < SPLITD; ++z) {
        const float* src = srcBase + (size_t)z * Bn * Un;
        #pragma unroll
        for (int r = 0; r < 4; ++r)
            sum[r] += *reinterpret_cast<const v4f*>(src + (size_t)r * Un);
    }
    float* dsto = outp + ((size_t)(bb + ty4) * Un + ub + tx4);
    #pragma unroll
    for (int r = 0; r < 4; ++r)
        *reinterpret_cast<v4f*>(dsto + (size_t)r * Un) = sum[r];
}

extern "C" void kernel_launch(void* const* d_in, const int* in_sizes, int n_in,
                              void* d_out, int out_size, void* d_ws, size_t ws_size,
                              hipStream_t stream) {
    const float* x = (const float*)d_in[0];
    const float* w = (const float*)d_in[1];
    const float* p = (const float*)d_in[2];
    const float* b = (const float*)d_in[3];
    float* out = (float*)d_out;
    float* wsf = (float*)d_ws;

    const size_t need16 = (size_t)16 * Bn * Un * sizeof(float);   // 32 MB
    const size_t need8  = (size_t)8  * Bn * Un * sizeof(float);   // 16 MB
    const dim3 blk(256);

    if (ws_size >= need16) {
        // 8 x 16 x 16 = 2048 blocks; at 8 blocks/CU the whole grid is resident
        power_layer<16, 1><<<dim3(Un / BU, Bn / BM, 16), blk, 0, stream>>>(x, w, p, b, out, wsf);
    } else if (ws_size >= need8) {
        power_layer<8, 1><<<dim3(Un / BU, Bn / BM, 8), blk, 0, stream>>>(x, w, p, b, out, wsf);
    } else {
        hipMemsetAsync(out, 0, (size_t)out_size * sizeof(float), stream);
        power_layer<8, 0><<<dim3(Un / BU, Bn / BM, 8), blk, 0, stream>>>(x, w, p, b, out, wsf);
    }
}

// Round 3
// 115.204 us; speedup vs baseline: 2.9788x; 2.9788x over previous
//
#include <hip/hip_runtime.h>
#include <math.h>

#define EPS 1e-9f

constexpr int Bn = 1024, Dn = 512, Un = 512;
constexpr int BM = 64;      // rows of B per block (4x4 per thread)
constexpr int BU = 64;      // cols of U per block
constexpr int DK = 16;      // k-chunk staged in LDS (16KB/block)
constexpr int NTILES = (Bn / BM) * (Un / BU);   // 128 output tiles

typedef float v4f __attribute__((ext_vector_type(4)));

// Split-K semaphores: zero-initialized (.bss); last-arriving block resets its
// slot to 0, so the invariant "all zeros between launches" survives graph replay.
__device__ int tile_cnt[NTILES];

// XOR swizzle for sL columns (proven: conflicts -> 0). Multiples of 8,
// preserves b128 alignment of 4-float groups.
__device__ __forceinline__ int swz(int d) { return ((d >> 2) & 3) << 3; }

// MODE 0: atomicAdd directly into out (small-ws fallback; out pre-zeroed)
// MODE 1: coherent (sc0/sc1) partial stores + relaxed semaphore + in-kernel tail.
//         NO __threadfence, NO acq/rel atomics: on gfx950 those lower to
//         buffer_wbl2 / buffer_inv (full local-L2 writeback/invalidate). 2048
//         blocks executing that nuked L2 for all resident blocks and took the
//         kernel 47.6us -> 290us (R1/R2: FETCH 9.8->28.9MB, VALUBusy 74->13%).
//         Relaxed agent atomic stores/loads carry sc0 sc1 per-access instead:
//         they bypass the non-coherent L2 and meet at the memory-side point,
//         leaving everyone else's cached tiles alone.
template <int SPLITD, int MODE>
__global__ __launch_bounds__(256, 4) void power_layer(
    const float* __restrict__ x, const float* __restrict__ w,
    const float* __restrict__ p, const float* __restrict__ bias,
    float* __restrict__ outp, float* __restrict__ wsp)
{
    constexpr int DPB    = Dn / SPLITD;
    constexpr int NCHUNK = DPB / DK;

    __shared__ float sL[DK][BM];   // sign(neg)*(log2|x+eps|+64), swizzled cols
    __shared__ float sP[DK][BU];   // p
    __shared__ float sW[DK][BU];   // w
    __shared__ float sWX[DK][BU];  // odd(p) ? -w : w

    const int tid = threadIdx.x;
    const int tx  = tid & 15;
    const int ty  = tid >> 4;
    const int tx4 = tx * 4;
    const int ty4 = ty * 4;
    const int ub = blockIdx.x * BU;
    const int bb = blockIdx.y * BM;
    const int d0 = blockIdx.z * DPB;

    // staging thread->element maps (chunk-invariant)
    const int xr  = tid >> 2;          // 0..63  (row for x tile)
    const int xdq = (tid & 3) << 2;    // 0,4,8,12 (d quad for x tile)
    const int pd  = tid >> 4;          // 0..15  (d for p/w tile)
    const int puq = (tid & 15) << 2;   // 0..60  (u quad for p/w tile)

    float4 xv, pv, wv;                 // global->reg prefetch (software pipeline)

    auto load_chunk = [&](int ch) {
        const int db = d0 + ch * DK;
        xv = *reinterpret_cast<const float4*>(&x[(size_t)(bb + xr) * Dn + db + xdq]);
        const size_t gi = (size_t)(db + pd) * Un + ub + puq;
        pv = *reinterpret_cast<const float4*>(&p[gi]);
        wv = *reinterpret_cast<const float4*>(&w[gi]);
    };

    auto stage_chunk = [&]() {
        const float* xs = reinterpret_cast<const float*>(&xv);
        #pragma unroll
        for (int j = 0; j < 4; ++j) {
            const float xe = xs[j] + EPS;
            const float La = __builtin_amdgcn_logf(fabsf(xe)) + 64.0f;
            const int dd = xdq + j;
            sL[dd][xr ^ swz(dd)] = (xe < 0.0f) ? -La : La;
        }
        const float* ps  = reinterpret_cast<const float*>(&pv);
        const float* wsv = reinterpret_cast<const float*>(&wv);
        float4 wxv;
        float* wxs = reinterpret_cast<float*>(&wxv);
        #pragma unroll
        for (int j = 0; j < 4; ++j) {
            const bool odd = (fmodf(ps[j], 2.0f) != 0.0f);
            wxs[j] = odd ? -wsv[j] : wsv[j];
        }
        *reinterpret_cast<float4*>(&sP[pd][puq])  = pv;
        *reinterpret_cast<float4*>(&sW[pd][puq])  = wv;
        *reinterpret_cast<float4*>(&sWX[pd][puq]) = wxv;
    };

    v4f acc[4] = {};   // 4 rows x 4 cols per thread

    load_chunk(0);
    stage_chunk();
    __syncthreads();

    for (int ch = 0; ch < NCHUNK; ++ch) {
        // issue next chunk's global loads now; latency hides under 16 d-iters
        if (ch + 1 < NCHUNK) load_chunk(ch + 1);

        // R0-proven inner loop: read BOTH w arrays as true LDS (ds_read_b128)
        // and select per element with v_cndmask (never select a pointer ->
        // flat_load demotion).
        #pragma unroll 2
        for (int d = 0; d < DK; ++d) {
            const v4f Lv = *reinterpret_cast<const v4f*>(&sL[d][ty4 ^ swz(d)]);
            const v4f Pv = *reinterpret_cast<const v4f*>(&sP[d][tx4]);
            const v4f Wv = *reinterpret_cast<const v4f*>(&sW[d][tx4]);
            const v4f Xv = *reinterpret_cast<const v4f*>(&sWX[d][tx4]);

            float Ld[4];
            bool  ng[4];
            #pragma unroll
            for (int r = 0; r < 4; ++r) {
                Ld[r] = fabsf(Lv[r]) - 64.0f;
                ng[r] = Lv[r] < 0.0f;
            }

            // batch all 16 independent exps before any consumer
            v4f e[4];
            #pragma unroll
            for (int r = 0; r < 4; ++r) {
                const v4f t = Pv * Ld[r];         // v_pk_mul_f32 x2
                #pragma unroll
                for (int c = 0; c < 4; ++c)
                    e[r][c] = __builtin_amdgcn_exp2f(t[c]);
            }

            #pragma unroll
            for (int r = 0; r < 4; ++r) {
                v4f wsel;
                #pragma unroll
                for (int c = 0; c < 4; ++c)
                    wsel[c] = ng[r] ? Xv[c] : Wv[c];   // v_cndmask
                acc[r] = __builtin_elementwise_fma(wsel, e[r], acc[r]);  // v_pk_fma x2
            }
        }
        __syncthreads();
        if (ch + 1 < NCHUNK) {
            stage_chunk();          // regs (loaded above) -> LDS
            __syncthreads();
        }
    }

    if (MODE == 0) {
        if (blockIdx.z == 0) {
            const v4f bv = *reinterpret_cast<const v4f*>(&bias[ub + tx4]);
            #pragma unroll
            for (int r = 0; r < 4; ++r)
                acc[r] += bv;
        }
        #pragma unroll
        for (int r = 0; r < 4; ++r) {
            const int row = bb + ty4 + r;
            #pragma unroll
            for (int c = 0; c < 4; ++c)
                atomicAdd(&outp[(size_t)row * Un + ub + tx4 + c], acc[r][c]);
        }
        return;
    }

    // ---- MODE 1: coherent partial stores, relaxed semaphore, fused tail ----
    {
        // relaxed agent atomic stores -> global_store_dword sc0 sc1:
        // bypass the (non-coherent) local L2, land at the shared point.
        float* dst = wsp + (((size_t)blockIdx.z * Bn + bb + ty4) * Un + ub + tx4);
        #pragma unroll
        for (int r = 0; r < 4; ++r)
            #pragma unroll
            for (int c = 0; c < 4; ++c)
                __hip_atomic_store(dst + (size_t)r * Un + c, acc[r][c],
                                   __ATOMIC_RELAXED, __HIP_MEMORY_SCOPE_AGENT);
    }

    // barrier lowering drains vmcnt(0): every wave's sc1 stores are at the
    // coherent point before any thread touches the semaphore.
    __syncthreads();

    __shared__ int s_last;
    if (tid == 0) {
        const int tile = blockIdx.y * (Un / BU) + blockIdx.x;
        const int old = __hip_atomic_fetch_add(&tile_cnt[tile], 1,
                            __ATOMIC_RELAXED, __HIP_MEMORY_SCOPE_AGENT);
        s_last = (old == SPLITD - 1) ? 1 : 0;
        if (old == SPLITD - 1)     // self-clean for the next launch/replay
            __hip_atomic_store(&tile_cnt[tile], 0, __ATOMIC_RELAXED,
                               __HIP_MEMORY_SCOPE_AGENT);
    }
    __syncthreads();
    if (!s_last) return;

    // Tail: read partials with relaxed agent atomic loads (sc0 sc1 -> bypass
    // stale L1/L2). Batch 16 loads into temporaries per z so they pipeline
    // before one waitcnt instead of serializing load->add->load->add.
    const v4f bv = *reinterpret_cast<const v4f*>(&bias[ub + tx4]);
    v4f sum[4] = {bv, bv, bv, bv};
    const float* srcBase = wsp + ((size_t)(bb + ty4) * Un + ub + tx4);
    for (int z = 0; z < SPLITD; ++z) {
        const float* src = srcBase + (size_t)z * Bn * Un;
        float t[16];
        #pragma unroll
        for (int r = 0; r < 4; ++r)
            #pragma unroll
            for (int c = 0; c < 4; ++c)
                t[r * 4 + c] = __hip_atomic_load(src + (size_t)r * Un + c,
                                   __ATOMIC_RELAXED, __HIP_MEMORY_SCOPE_AGENT);
        #pragma unroll
        for (int r = 0; r < 4; ++r)
            #pragma unroll
            for (int c = 0; c < 4; ++c)
                sum[r][c] += t[r * 4 + c];
    }
    float* dsto = outp + ((size_t)(bb + ty4) * Un + ub + tx4);
    #pragma unroll
    for (int r = 0; r < 4; ++r)
        *reinterpret_cast<v4f*>(dsto + (size_t)r * Un) = sum[r];
}

extern "C" void kernel_launch(void* const* d_in, const int* in_sizes, int n_in,
                              void* d_out, int out_size, void* d_ws, size_t ws_size,
                              hipStream_t stream) {
    const float* x = (const float*)d_in[0];
    const float* w = (const float*)d_in[1];
    const float* p = (const float*)d_in[2];
    const float* b = (const float*)d_in[3];
    float* out = (float*)d_out;
    float* wsf = (float*)d_ws;

    const size_t need8 = (size_t)8 * Bn * Un * sizeof(float);   // 16 MB
    const dim3 blk(256);

    if (ws_size >= need8) {
        // SPLITD=8: 8 x 16 x 8 = 1024 blocks = exactly 4/CU at (256,4):
        // whole grid co-resident in ONE round, all 8 z-slices of a tile
        // concurrent (short semaphore waits), VGPR budget 128.
        power_layer<8, 1><<<dim3(Un / BU, Bn / BM, 8), blk, 0, stream>>>(x, w, p, b, out, wsf);
    } else {
        hipMemsetAsync(out, 0, (size_t)out_size * sizeof(float), stream);
        power_layer<8, 0><<<dim3(Un / BU, Bn / BM, 8), blk, 0, stream>>>(x, w, p, b, out, wsf);
    }
}

// Round 4
// 111.873 us; speedup vs baseline: 3.0675x; 1.0298x over previous
//
#include <hip/hip_runtime.h>
#include <math.h>

#define EPS 1e-9f

constexpr int Bn = 1024, Dn = 512, Un = 512;
constexpr int BM = 64;      // rows of B per block (4x4 per thread)
constexpr int BU = 64;      // cols of U per block
constexpr int DK = 16;      // k-chunk staged in LDS (16KB/block)
constexpr int NTILES = (Bn / BM) * (Un / BU);   // 128 output tiles

typedef float v4f __attribute__((ext_vector_type(4)));

// Split-K semaphores: zero-initialized (.bss); last-arriving block resets its
// slot to 0, so the invariant "all zeros between launches" survives graph replay.
__device__ int tile_cnt[NTILES];

// XOR swizzle for sL columns (proven: conflicts -> 0). Multiples of 8,
// preserves b128 alignment of 4-float groups.
__device__ __forceinline__ int swz(int d) { return ((d >> 2) & 3) << 3; }

// Coherent 16B store: bypasses the non-coherent local L2 (sc0 sc1), but keeps
// full vector width -> wave-contiguous 256B segments, no write amplification
// (R3's scalar __hip_atomic_store partials: WRITE_SIZE 68.9MB vs 18MB ideal).
__device__ __forceinline__ void store_coherent_v4(float* addr, v4f v) {
    asm volatile("global_store_dwordx4 %0, %1, off sc0 sc1"
                 :: "v"(addr), "v"(v) : "memory");
}

// MODE 0: atomicAdd directly into out (small-ws fallback; out pre-zeroed)
// MODE 1: coherent dwordx4 partial stores + relaxed semaphore + fused tail.
//   Coherence recipe (learned R1->R3):
//   - NO __threadfence / acq-rel RMW in the hot path: those lower to
//     buffer_wbl2/buffer_inv per block (full local-L2 writeback+invalidate);
//     2048 of them mid-flight nuked everyone's cached tiles (47.6->290us).
//   - writers: sc0/sc1 vector stores go straight to the coherent point; each
//     wave drains its own vmcnt before the barrier, so the relaxed semaphore
//     increment happens-after the data is globally visible.
//   - the ONE tail block per tile does a single agent-scope ACQUIRE (one
//     buffer_inv, 128 total near kernel end) and then reads partials with
//     normal cached loads the compiler can pipeline.
template <int SPLITD, int MODE>
__global__ __launch_bounds__(256, 4) void power_layer(
    const float* __restrict__ x, const float* __restrict__ w,
    const float* __restrict__ p, const float* __restrict__ bias,
    float* __restrict__ outp, float* __restrict__ wsp)
{
    constexpr int DPB    = Dn / SPLITD;
    constexpr int NCHUNK = DPB / DK;

    __shared__ float sL[DK][BM];   // sign(neg)*(log2|x+eps|+64), swizzled cols
    __shared__ float sP[DK][BU];   // p
    __shared__ float sW[DK][BU];   // w
    __shared__ float sWX[DK][BU];  // odd(p) ? -w : w

    const int tid = threadIdx.x;
    const int tx  = tid & 15;
    const int ty  = tid >> 4;
    const int tx4 = tx * 4;
    const int ty4 = ty * 4;
    const int ub = blockIdx.x * BU;
    const int bb = blockIdx.y * BM;
    const int d0 = blockIdx.z * DPB;

    // staging thread->element maps (chunk-invariant)
    const int xr  = tid >> 2;          // 0..63  (row for x tile)
    const int xdq = (tid & 3) << 2;    // 0,4,8,12 (d quad for x tile)
    const int pd  = tid >> 4;          // 0..15  (d for p/w tile)
    const int puq = (tid & 15) << 2;   // 0..60  (u quad for p/w tile)

    float4 xv, pv, wv;                 // global->reg prefetch (software pipeline)

    auto load_chunk = [&](int ch) {
        const int db = d0 + ch * DK;
        xv = *reinterpret_cast<const float4*>(&x[(size_t)(bb + xr) * Dn + db + xdq]);
        const size_t gi = (size_t)(db + pd) * Un + ub + puq;
        pv = *reinterpret_cast<const float4*>(&p[gi]);
        wv = *reinterpret_cast<const float4*>(&w[gi]);
    };

    auto stage_chunk = [&]() {
        const float* xs = reinterpret_cast<const float*>(&xv);
        #pragma unroll
        for (int j = 0; j < 4; ++j) {
            const float xe = xs[j] + EPS;
            const float La = __builtin_amdgcn_logf(fabsf(xe)) + 64.0f;
            const int dd = xdq + j;
            sL[dd][xr ^ swz(dd)] = (xe < 0.0f) ? -La : La;
        }
        const float* ps  = reinterpret_cast<const float*>(&pv);
        const float* wsv = reinterpret_cast<const float*>(&wv);
        float4 wxv;
        float* wxs = reinterpret_cast<float*>(&wxv);
        #pragma unroll
        for (int j = 0; j < 4; ++j) {
            const bool odd = (fmodf(ps[j], 2.0f) != 0.0f);
            wxs[j] = odd ? -wsv[j] : wsv[j];
        }
        *reinterpret_cast<float4*>(&sP[pd][puq])  = pv;
        *reinterpret_cast<float4*>(&sW[pd][puq])  = wv;
        *reinterpret_cast<float4*>(&sWX[pd][puq]) = wxv;
    };

    v4f acc[4] = {};   // 4 rows x 4 cols per thread

    load_chunk(0);
    stage_chunk();
    __syncthreads();

    for (int ch = 0; ch < NCHUNK; ++ch) {
        // issue next chunk's global loads now; latency hides under 16 d-iters
        if (ch + 1 < NCHUNK) load_chunk(ch + 1);

        // R0-proven inner loop: read BOTH w arrays as true LDS (ds_read_b128)
        // and select per element with v_cndmask (never select a pointer ->
        // flat_load demotion, R1).
        #pragma unroll 2
        for (int d = 0; d < DK; ++d) {
            const v4f Lv = *reinterpret_cast<const v4f*>(&sL[d][ty4 ^ swz(d)]);
            const v4f Pv = *reinterpret_cast<const v4f*>(&sP[d][tx4]);
            const v4f Wv = *reinterpret_cast<const v4f*>(&sW[d][tx4]);
            const v4f Xv = *reinterpret_cast<const v4f*>(&sWX[d][tx4]);

            float Ld[4];
            bool  ng[4];
            #pragma unroll
            for (int r = 0; r < 4; ++r) {
                Ld[r] = fabsf(Lv[r]) - 64.0f;
                ng[r] = Lv[r] < 0.0f;
            }

            // batch all 16 independent exps before any consumer
            v4f e[4];
            #pragma unroll
            for (int r = 0; r < 4; ++r) {
                const v4f t = Pv * Ld[r];         // v_pk_mul_f32 x2
                #pragma unroll
                for (int c = 0; c < 4; ++c)
                    e[r][c] = __builtin_amdgcn_exp2f(t[c]);
            }

            #pragma unroll
            for (int r = 0; r < 4; ++r) {
                v4f wsel;
                #pragma unroll
                for (int c = 0; c < 4; ++c)
                    wsel[c] = ng[r] ? Xv[c] : Wv[c];   // v_cndmask
                acc[r] = __builtin_elementwise_fma(wsel, e[r], acc[r]);  // v_pk_fma x2
            }
        }
        __syncthreads();
        if (ch + 1 < NCHUNK) {
            stage_chunk();          // regs (loaded above) -> LDS
            __syncthreads();
        }
    }

    if (MODE == 0) {
        if (blockIdx.z == 0) {
            const v4f bv = *reinterpret_cast<const v4f*>(&bias[ub + tx4]);
            #pragma unroll
            for (int r = 0; r < 4; ++r)
                acc[r] += bv;
        }
        #pragma unroll
        for (int r = 0; r < 4; ++r) {
            const int row = bb + ty4 + r;
            #pragma unroll
            for (int c = 0; c < 4; ++c)
                atomicAdd(&outp[(size_t)row * Un + ub + tx4 + c], acc[r][c]);
        }
        return;
    }

    // ---- MODE 1: coherent vector partial stores, relaxed semaphore, tail ----
    {
        float* dst = wsp + (((size_t)blockIdx.z * Bn + bb + ty4) * Un + ub + tx4);
        #pragma unroll
        for (int r = 0; r < 4; ++r)
            store_coherent_v4(dst + (size_t)r * Un, acc[r]);
    }
    // each wave drains its own coherent stores; barrier then orders all waves'
    // drains before the semaphore increment.
    asm volatile("s_waitcnt vmcnt(0)" ::: "memory");
    __syncthreads();

    const int tile = blockIdx.y * (Un / BU) + blockIdx.x;
    __shared__ int s_last;
    if (tid == 0) {
        const int old = __hip_atomic_fetch_add(&tile_cnt[tile], 1,
                            __ATOMIC_RELAXED, __HIP_MEMORY_SCOPE_AGENT);
        s_last = (old == SPLITD - 1) ? 1 : 0;
        if (old == SPLITD - 1)     // self-clean for the next launch/replay
            __hip_atomic_store(&tile_cnt[tile], 0, __ATOMIC_RELAXED,
                               __HIP_MEMORY_SCOPE_AGENT);
    }
    __syncthreads();
    if (!s_last) return;

    // single agent-scope acquire: one buffer_inv per tail block (128 total,
    // at end of kernel life) -> local L1/L2 stale lines dropped; partials are
    // already at the coherent point (writers' sc0/sc1 stores + vmcnt drain
    // happened-before their semaphore increments).
    if (tid == 0)
        (void)__hip_atomic_load(&tile_cnt[tile], __ATOMIC_ACQUIRE,
                                __HIP_MEMORY_SCOPE_AGENT);
    __syncthreads();

    // normal cached dwordx4 loads: compiler pipelines them (64 per thread)
    const v4f bv = *reinterpret_cast<const v4f*>(&bias[ub + tx4]);
    v4f sum[4] = {bv, bv, bv, bv};
    const float* srcBase = wsp + ((size_t)(bb + ty4) * Un + ub + tx4);
    #pragma unroll 4
    for (int z = 0; z < SPLITD; ++z) {
        const float* src = srcBase + (size_t)z * Bn * Un;
        v4f t[4];
        #pragma unroll
        for (int r = 0; r < 4; ++r)
            t[r] = *reinterpret_cast<const v4f*>(src + (size_t)r * Un);
        #pragma unroll
        for (int r = 0; r < 4; ++r)
            sum[r] += t[r];
    }
    float* dsto = outp + ((size_t)(bb + ty4) * Un + ub + tx4);
    #pragma unroll
    for (int r = 0; r < 4; ++r)
        *reinterpret_cast<v4f*>(dsto + (size_t)r * Un) = sum[r];
}

extern "C" void kernel_launch(void* const* d_in, const int* in_sizes, int n_in,
                              void* d_out, int out_size, void* d_ws, size_t ws_size,
                              hipStream_t stream) {
    const float* x = (const float*)d_in[0];
    const float* w = (const float*)d_in[1];
    const float* p = (const float*)d_in[2];
    const float* b = (const float*)d_in[3];
    float* out = (float*)d_out;
    float* wsf = (float*)d_ws;

    const size_t need16 = (size_t)16 * Bn * Un * sizeof(float);   // 32 MB
    const size_t need8  = (size_t)8  * Bn * Un * sizeof(float);   // 16 MB
    const dim3 blk(256);

    if (ws_size >= need16) {
        // SPLITD=16: 8 x 16 x 16 = 2048 blocks -> R0-proven parallelism
        // (VALUBusy 74%); R3's SPLITD=8/1024 blocks dropped it to 58%.
        power_layer<16, 1><<<dim3(Un / BU, Bn / BM, 16), blk, 0, stream>>>(x, w, p, b, out, wsf);
    } else if (ws_size >= need8) {
        power_layer<8, 1><<<dim3(Un / BU, Bn / BM, 8), blk, 0, stream>>>(x, w, p, b, out, wsf);
    } else {
        hipMemsetAsync(out, 0, (size_t)out_size * sizeof(float), stream);
        power_layer<8, 0><<<dim3(Un / BU, Bn / BM, 8), blk, 0, stream>>>(x, w, p, b, out, wsf);
    }
}